// Round 7
// baseline (511.510 us; speedup 1.0000x reference)
//
#include <hip/hip_runtime.h>

// out = x + 0.002 * einsum('bci,bij->bcj', f, softmax_i(einsum('bci,bcj->bij', f, f)))
// x: [8, 128, 64, 64] fp32.  b=8, c=d=128, n=wh=4096.
// Flash attention, Q=K=V=Ft. 32x32x16 MFMA, 32 q-rows/wave, P in registers
// (lane^32 exchange), XOR-swizzled LDS K/V tiles, XCD = batch.
// r7: 1024-thr blocks (16 waves = 4wq x 4wk), KVB=128, 128KB dbuf LDS,
//     4 waves/SIMD occupancy (was 2). ws: ft bf16 [b][n][c] = 8 MB.

typedef __bf16 bf16;
typedef bf16 bf16x2 __attribute__((ext_vector_type(2)));
typedef bf16 bf16x4 __attribute__((ext_vector_type(4)));
typedef bf16 bf16x8 __attribute__((ext_vector_type(8)));
typedef float f32x4 __attribute__((ext_vector_type(4)));
typedef float f32x16 __attribute__((ext_vector_type(16)));
typedef unsigned int u32;
typedef u32 u32x4 __attribute__((ext_vector_type(4)));

#define BATCH 8
#define CD 128
#define NN 4096
#define QBLK 128
#define KVB 128
#define NT (NN / KVB)
#define LOG2E 1.44269504f

// XOR swizzle (T2): 16-B granule, bijective per row, same map on write & read.
// kt rows: 128 c * 2B = 256 B.  vt rows: 128 keys * 2B = 256 B.
#define KT_BY(row, colb) (((row) << 8) + ((colb) ^ (((row) & 7) << 4)))
#define VT_BY(row, colb) (((row) << 8) + ((colb) ^ (((row) & 7) << 4)))

// ---------- kernel 1: ft[b][n][c] = bf16(x[b][c][n]) — LDS-free transpose ----------
__global__ __launch_bounds__(256) void transpose_to_bf16(const float* __restrict__ x,
                                                         bf16* __restrict__ ft) {
    const u32 g  = blockIdx.x * 256 + threadIdx.x;   // 8*4096*16 = 524288 slots
    const u32 b  = g >> 16;
    const u32 r  = g & 65535;
    const u32 n_lo  = r & 15;
    const u32 c8_lo = (r >> 4) & 3;
    const u32 hi    = r >> 6;
    const u32 c8 = (hi & 3) * 4 + c8_lo;             // 0..15
    const u32 n  = (hi >> 2) * 16 + n_lo;            // 0..4095
    const float* xb = x + (size_t)b * CD * NN;
    bf16x8 o;
#pragma unroll
    for (int e = 0; e < 8; e++)
        o[e] = (bf16)xb[(size_t)(c8 * 8 + e) * NN + n];
    *reinterpret_cast<bf16x8*>(ft + ((size_t)b * NN + n) * CD + c8 * 8) = o;
}

// ---------- kernel 2: flash attention + fused residual ----------
// 256 blocks (XCD=batch, 32 q-tiles of 128), 1024 threads = 16 waves (4wq x 4wk).
// Wave: 32 q-rows x 32 keys per iter, 16 MFMA (32x32x16), KV tile 128, dbuf LDS.
__global__ __launch_bounds__(1024, 4) void attn_kernel(const float* __restrict__ x,
                                                       const bf16* __restrict__ ft,
                                                       float* __restrict__ out) {
    const int tid = threadIdx.x;
    const int w   = tid >> 6;
    const int wq  = w & 3;      // q-group: 32 rows
    const int wk  = w >> 2;     // key-quarter: 32 keys
    const int l   = tid & 63;
    const int l31 = l & 31;
    const int h   = l >> 5;

    const int batch = blockIdx.x & 7;            // round-robin dispatch -> XCD = batch
    const int q0    = (blockIdx.x >> 3) * QBLK;

    const bf16*  ftb  = ft  + (size_t)batch * NN * CD;
    const float* xb   = x   + (size_t)batch * CD * NN;
    float*       outb = out + (size_t)batch * CD * NN;

    __shared__ union {
        struct {
            bf16 kt[2][KVB * 128];   // [key][c] swizzled, 32 KB/buf
            bf16 vt[2][CD * KVB];    // [c][key] swizzled, 32 KB/buf
        } s;
        float o[CD][132];            // epilogue O merge [c][q], 16B-aligned rows
    } sm;
    __shared__ float s_mx[16][32], s_ls[16][32];

    // Q frags (B-operand): q = q0+wq*32+l31, c = kst*16 + h*8 + e; folded log2e
    bf16x8 qf[8];
    {
        const bf16* qp = ftb + (size_t)(q0 + wq * 32 + l31) * CD + h * 8;
#pragma unroll
        for (int kst = 0; kst < 8; kst++) {
            bf16x8 t = *reinterpret_cast<const bf16x8*>(qp + kst * 16);
#pragma unroll
            for (int e = 0; e < 8; e++) qf[kst][e] = (bf16)((float)t[e] * LOG2E);
        }
    }

    // ---- staging: kt (from ft, bf16 copy) + vt (from x, f32->bf16) ----
    bf16x8 kreg[2];
    f32x4  vreg[4];
    auto stage_load = [&](int i0) {
#pragma unroll
        for (int j = 0; j < 2; j++) {                 // kt: 128 rows x 256B
            const int slot = tid + j * 1024;
            kreg[j] = *reinterpret_cast<const bf16x8*>(
                ftb + (size_t)(i0 + (slot >> 4)) * CD + (slot & 15) * 8);
        }
#pragma unroll
        for (int j = 0; j < 4; j++) {                 // vt: 128 c-rows x 128 keys (f32)
            const int slot = tid + j * 1024;
            vreg[j] = *reinterpret_cast<const f32x4*>(
                xb + (size_t)(slot >> 5) * NN + i0 + (slot & 31) * 4);
        }
    };
    auto stage_write = [&](int buf) {
        char* ktb = (char*)sm.s.kt[buf];
        char* vtb = (char*)sm.s.vt[buf];
#pragma unroll
        for (int j = 0; j < 2; j++) {
            const int slot = tid + j * 1024;
            *reinterpret_cast<bf16x8*>(ktb + KT_BY(slot >> 4, (slot & 15) * 16)) = kreg[j];
        }
#pragma unroll
        for (int j = 0; j < 4; j++) {
            const int slot = tid + j * 1024;
            bf16x4 t;
#pragma unroll
            for (int e = 0; e < 4; e++) t[e] = (bf16)vreg[j][e];
            *reinterpret_cast<bf16x4*>(vtb + VT_BY(slot >> 5, (slot & 31) * 8)) = t;
        }
    };

    f32x16 oacc[4];
#pragma unroll
    for (int ct = 0; ct < 4; ct++)
#pragma unroll
        for (int r = 0; r < 16; r++) oacc[ct][r] = 0.0f;
    float m_run = -1e30f;   // running max (log2 units) for q = l31
    float l_par = 0.0f;     // per-lane partial denominator (16-key share)

    stage_load(0);
    stage_write(0);
    __syncthreads();

    for (int it = 0; it < NT; ++it) {
        const int cur = it & 1;
        if (it + 1 < NT) stage_load((it + 1) * KVB);   // in flight under compute (T14)

        const char* ktb = (const char*)sm.s.kt[cur];
        const char* vtb = (const char*)sm.s.vt[cur];

        // ---- QK^T: S'[key=wk*32+rowmap][q=l31], 8 MFMA, 2 acc chains ----
        f32x16 sA, sB;
#pragma unroll
        for (int r = 0; r < 16; r++) { sA[r] = 0.0f; sB[r] = 0.0f; }
        __builtin_amdgcn_s_setprio(1);
#pragma unroll
        for (int kst = 0; kst < 8; kst += 2) {
            bf16x8 kf0 = *reinterpret_cast<const bf16x8*>(
                ktb + KT_BY(wk * 32 + l31, kst * 32 + h * 16));
            bf16x8 kf1 = *reinterpret_cast<const bf16x8*>(
                ktb + KT_BY(wk * 32 + l31, (kst + 1) * 32 + h * 16));
            sA = __builtin_amdgcn_mfma_f32_32x32x16_bf16(kf0, qf[kst], sA, 0, 0, 0);
            sB = __builtin_amdgcn_mfma_f32_32x32x16_bf16(kf1, qf[kst + 1], sB, 0, 0, 0);
        }
        __builtin_amdgcn_s_setprio(0);
        float s[16];
#pragma unroll
        for (int r = 0; r < 16; r++) s[r] = sA[r] + sB[r];
        // lane holds k_local = (r&3) + 8*(r>>2) + 4*h (of wave's 32 keys), q = l31

        // ---- softmax over keys (log2 space), in-register ----
        float mp = s[0];
#pragma unroll
        for (int r = 1; r < 16; r++) mp = fmaxf(mp, s[r]);
        mp = fmaxf(mp, __shfl_xor(mp, 32));

        if (__any(mp > m_run + 11.5f)) {   // defer-max (T13): rescale rarely
            const float mn = fmaxf(m_run, mp);
            const float al = exp2f(m_run - mn);
            m_run = mn;
            l_par *= al;
#pragma unroll
            for (int ct = 0; ct < 4; ct++)
#pragma unroll
                for (int r = 0; r < 16; r++) oacc[ct][r] *= al;   // same q/lane: no shuffle
        }

        float pe[16];
        float ps = 0.0f;
#pragma unroll
        for (int r = 0; r < 16; r++) { pe[r] = exp2f(s[r] - m_run); ps += pe[r]; }
        l_par += ps;

        // ---- P -> PV A-frags fully in registers (lane<->lane^32 exchange) ----
        u32 W[4][2], Xs[4][2];
#pragma unroll
        for (int gg = 0; gg < 4; gg++)
#pragma unroll
            for (int j = 0; j < 2; j++) {
                bf16x2 t = {(bf16)pe[4 * gg + 2 * j], (bf16)pe[4 * gg + 2 * j + 1]};
                W[gg][j] = __builtin_bit_cast(unsigned short, t[0]) |
                           ((u32)__builtin_bit_cast(unsigned short, t[1]) << 16);
                Xs[gg][j] = (u32)__shfl_xor((int)W[gg][j], 32);
            }
        u32x4 pw0 = {h ? Xs[1][0] : W[0][0], h ? Xs[1][1] : W[0][1],
                     h ? W[1][0] : Xs[0][0], h ? W[1][1] : Xs[0][1]};
        u32x4 pw1 = {h ? Xs[3][0] : W[2][0], h ? Xs[3][1] : W[2][1],
                     h ? W[3][0] : Xs[2][0], h ? W[3][1] : Xs[2][1]};
        bf16x8 pa0 = __builtin_bit_cast(bf16x8, pw0);
        bf16x8 pa1 = __builtin_bit_cast(bf16x8, pw1);

        // ---- PV: O[q][c] over this wave's 32 keys, 8 MFMA ----
        __builtin_amdgcn_s_setprio(1);
#pragma unroll
        for (int ct = 0; ct < 4; ct++) {
            bf16x8 vf0 = *reinterpret_cast<const bf16x8*>(
                vtb + VT_BY(ct * 32 + l31, wk * 64 + h * 16));
            oacc[ct] = __builtin_amdgcn_mfma_f32_32x32x16_bf16(pa0, vf0, oacc[ct], 0, 0, 0);
            bf16x8 vf1 = *reinterpret_cast<const bf16x8*>(
                vtb + VT_BY(ct * 32 + l31, wk * 64 + 32 + h * 16));
            oacc[ct] = __builtin_amdgcn_mfma_f32_32x32x16_bf16(pa1, vf1, oacc[ct], 0, 0, 0);
        }
        __builtin_amdgcn_s_setprio(0);

        if (it + 1 < NT) stage_write(cur ^ 1);   // vmcnt wait lands here
        __syncthreads();
    }

    // ---- epilogue: merge lane pair, then 4 wk quarters; normalize; residual ----
    const float Lp = l_par + __shfl_xor(l_par, 32);   // m_run identical across pair
    if (l < 32) { s_mx[w][l31] = m_run; s_ls[w][l31] = Lp; }
    __syncthreads();

    float m_p = m_run;
#pragma unroll
    for (int j = 0; j < 4; j++) m_p = fmaxf(m_p, s_mx[wq + 4 * j][l31]);
    float Lt = 0.0f;
#pragma unroll
    for (int j = 0; j < 4; j++)
        Lt += s_ls[wq + 4 * j][l31] * exp2f(s_mx[wq + 4 * j][l31] - m_p);
    const float fsc = exp2f(m_run - m_p) / Lt;       // per-lane, q-local

    // O accumulate into sm.o[c][q] over 4 wk phases
#pragma unroll
    for (int ph = 0; ph < 4; ph++) {
        if (wk == ph) {
#pragma unroll
            for (int ct = 0; ct < 4; ct++)
#pragma unroll
                for (int r = 0; r < 16; r++) {
                    const int c = ct * 32 + (r & 3) + 8 * (r >> 2) + 4 * h;
                    const float v = oacc[ct][r] * fsc;
                    if (ph == 0) sm.o[c][wq * 32 + l31] = v;
                    else         sm.o[c][wq * 32 + l31] += v;
                }
        }
        __syncthreads();
    }

    // fused residual: out[c][q] = x + 0.002*O, f32x4 along q
#pragma unroll
    for (int k = 0; k < 4; k++) {
        const int slot = tid + k * 1024;         // 4096 slots: c = slot>>5, q4 = slot&31
        const int c  = slot >> 5;
        const int q4 = (slot & 31) * 4;
        f32x4 xv = *reinterpret_cast<const f32x4*>(xb + (size_t)c * NN + q0 + q4);
        f32x4 oo = *reinterpret_cast<const f32x4*>(&sm.o[c][q4]);
        f32x4 ov;
#pragma unroll
        for (int e = 0; e < 4; e++)
            ov[e] = xv[e] + 0.002f * oo[e];
        *reinterpret_cast<f32x4*>(outb + (size_t)c * NN + q0 + q4) = ov;
    }
}

extern "C" void kernel_launch(void* const* d_in, const int* in_sizes, int n_in,
                              void* d_out, int out_size, void* d_ws, size_t ws_size,
                              hipStream_t stream) {
    const float* x = (const float*)d_in[0];
    float* out = (float*)d_out;
    bf16* ft = (bf16*)d_ws;   // 8 MB

    transpose_to_bf16<<<2048, 256, 0, stream>>>(x, ft);
    attn_kernel<<<256, 1024, 0, stream>>>(x, ft, out);
}

// Round 9
// 195.902 us; speedup vs baseline: 2.6111x; 2.6111x over previous
//
#include <hip/hip_runtime.h>

// out = x + 0.002 * einsum('bci,bij->bcj', f, softmax_i(einsum('bci,bcj->bij', f, f)))
// x: [8, 128, 64, 64] fp32.  b=8, c=d=128, n=wh=4096.
// Flash attention, Q=K=V=Ft. 32x32x16 MFMA, 32 q-rows/wave, P in registers
// (lane^32 exchange), XOR-swizzled LDS K/V tiles, XCD = batch.
// r9 = r8 + epilogue bounds fix (k<8: 2048 slots, c<128 — r8 wrote c up to 255 OOB).
// 256-thr blocks (4 waves = 2wq x 2wk), QBLK=64, KVB=64, grid=512
// -> TWO independent blocks per CU (barrier-decoupled overlap).
// ws: ft bf16 [b][n][c] = 8 MB.

typedef __bf16 bf16;
typedef bf16 bf16x2 __attribute__((ext_vector_type(2)));
typedef bf16 bf16x4 __attribute__((ext_vector_type(4)));
typedef bf16 bf16x8 __attribute__((ext_vector_type(8)));
typedef float f32x4 __attribute__((ext_vector_type(4)));
typedef float f32x16 __attribute__((ext_vector_type(16)));
typedef unsigned int u32;
typedef u32 u32x4 __attribute__((ext_vector_type(4)));

#define BATCH 8
#define CD 128
#define NN 4096
#define QBLK 64
#define KVB 64
#define NT (NN / KVB)
#define LOG2E 1.44269504f

// XOR swizzle (T2): 16-B granule, bijective per row, same map on write & read.
#define KT_BY(row, colb) (((row) << 8) + ((colb) ^ (((row) & 7) << 4)))  // 256 B rows
#define VT_BY(row, colb) (((row) << 7) + ((colb) ^ (((row) & 7) << 4)))  // 128 B rows

// ---------- kernel 1: ft[b][n][c] = bf16(x[b][c][n]) — LDS-free transpose ----------
__global__ __launch_bounds__(256) void transpose_to_bf16(const float* __restrict__ x,
                                                         bf16* __restrict__ ft) {
    const u32 g  = blockIdx.x * 256 + threadIdx.x;   // 8*4096*16 = 524288 slots
    const u32 b  = g >> 16;
    const u32 r  = g & 65535;
    const u32 n_lo  = r & 15;
    const u32 c8_lo = (r >> 4) & 3;
    const u32 hi    = r >> 6;
    const u32 c8 = (hi & 3) * 4 + c8_lo;             // 0..15
    const u32 n  = (hi >> 2) * 16 + n_lo;            // 0..4095
    const float* xb = x + (size_t)b * CD * NN;
    bf16x8 o;
#pragma unroll
    for (int e = 0; e < 8; e++)
        o[e] = (bf16)xb[(size_t)(c8 * 8 + e) * NN + n];
    *reinterpret_cast<bf16x8*>(ft + ((size_t)b * NN + n) * CD + c8 * 8) = o;
}

// ---------- kernel 2: flash attention + fused residual ----------
// 512 blocks (XCD=batch, 64 q-tiles of 64), 256 threads = 4 waves (2wq x 2wk).
// Wave: 32 q-rows x 32 keys per iter, 16 MFMA (32x32x16), KV tile 64, dbuf LDS.
__global__ __launch_bounds__(256, 2) void attn_kernel(const float* __restrict__ x,
                                                      const bf16* __restrict__ ft,
                                                      float* __restrict__ out) {
    const int tid = threadIdx.x;
    const int w   = tid >> 6;
    const int wq  = w & 1;      // q-group: 32 rows
    const int wk  = w >> 1;     // key-half: 32 keys
    const int l   = tid & 63;
    const int l31 = l & 31;
    const int h   = l >> 5;

    const int batch = blockIdx.x & 7;            // round-robin dispatch -> XCD = batch
    const int q0    = (blockIdx.x >> 3) * QBLK;

    const bf16*  ftb  = ft  + (size_t)batch * NN * CD;
    const float* xb   = x   + (size_t)batch * CD * NN;
    float*       outb = out + (size_t)batch * CD * NN;

    __shared__ union {
        struct {
            bf16 kt[2][KVB * 128];   // [key][c] swizzled, 16 KB/buf
            bf16 vt[2][CD * KVB];    // [c][key] swizzled, 16 KB/buf
        } s;
        float o[CD][68];             // epilogue O merge [c][q], 272 B rows
    } sm;
    __shared__ float s_mx[4][32], s_ls[4][32];

    // Q frags (B-operand): q = q0+wq*32+l31, c = kst*16 + h*8 + e; folded log2e
    bf16x8 qf[8];
    {
        const bf16* qp = ftb + (size_t)(q0 + wq * 32 + l31) * CD + h * 8;
#pragma unroll
        for (int kst = 0; kst < 8; kst++) {
            bf16x8 t = *reinterpret_cast<const bf16x8*>(qp + kst * 16);
#pragma unroll
            for (int e = 0; e < 8; e++) qf[kst][e] = (bf16)((float)t[e] * LOG2E);
        }
    }

    // ---- staging: kt (from ft, bf16 copy) + vt (from x, f32->bf16) ----
    bf16x8 kreg[4];
    f32x4  vreg[8];
    auto stage_load = [&](int i0) {
#pragma unroll
        for (int j = 0; j < 4; j++) {                 // kt: 64 rows x 256B
            const int slot = tid + j * 256;
            kreg[j] = *reinterpret_cast<const bf16x8*>(
                ftb + (size_t)(i0 + (slot >> 4)) * CD + (slot & 15) * 8);
        }
#pragma unroll
        for (int j = 0; j < 8; j++) {                 // vt: 128 c-rows x 64 keys (f32)
            const int slot = tid + j * 256;
            vreg[j] = *reinterpret_cast<const f32x4*>(
                xb + (size_t)(slot >> 4) * NN + i0 + (slot & 15) * 4);
        }
    };
    auto stage_write = [&](int buf) {
        char* ktb = (char*)sm.s.kt[buf];
        char* vtb = (char*)sm.s.vt[buf];
#pragma unroll
        for (int j = 0; j < 4; j++) {
            const int slot = tid + j * 256;
            *reinterpret_cast<bf16x8*>(ktb + KT_BY(slot >> 4, (slot & 15) * 16)) = kreg[j];
        }
#pragma unroll
        for (int j = 0; j < 8; j++) {
            const int slot = tid + j * 256;
            bf16x4 t;
#pragma unroll
            for (int e = 0; e < 4; e++) t[e] = (bf16)vreg[j][e];
            *reinterpret_cast<bf16x4*>(vtb + VT_BY(slot >> 4, (slot & 15) * 8)) = t;
        }
    };

    f32x16 oacc[4];
#pragma unroll
    for (int ct = 0; ct < 4; ct++)
#pragma unroll
        for (int r = 0; r < 16; r++) oacc[ct][r] = 0.0f;
    float m_run = -1e30f;   // running max (log2 units) for q = l31
    float l_par = 0.0f;     // per-lane partial denominator (16-key share)

    stage_load(0);
    stage_write(0);
    __syncthreads();

    for (int it = 0; it < NT; ++it) {
        const int cur = it & 1;
        if (it + 1 < NT) stage_load((it + 1) * KVB);   // in flight under compute (T14)

        const char* ktb = (const char*)sm.s.kt[cur];
        const char* vtb = (const char*)sm.s.vt[cur];

        // ---- QK^T: S'[key=wk*32+rowmap][q=l31], 8 MFMA, 2 acc chains ----
        f32x16 sA, sB;
#pragma unroll
        for (int r = 0; r < 16; r++) { sA[r] = 0.0f; sB[r] = 0.0f; }
        __builtin_amdgcn_s_setprio(1);
#pragma unroll
        for (int kst = 0; kst < 8; kst += 2) {
            bf16x8 kf0 = *reinterpret_cast<const bf16x8*>(
                ktb + KT_BY(wk * 32 + l31, kst * 32 + h * 16));
            bf16x8 kf1 = *reinterpret_cast<const bf16x8*>(
                ktb + KT_BY(wk * 32 + l31, (kst + 1) * 32 + h * 16));
            sA = __builtin_amdgcn_mfma_f32_32x32x16_bf16(kf0, qf[kst], sA, 0, 0, 0);
            sB = __builtin_amdgcn_mfma_f32_32x32x16_bf16(kf1, qf[kst + 1], sB, 0, 0, 0);
        }
        __builtin_amdgcn_s_setprio(0);
        float s[16];
#pragma unroll
        for (int r = 0; r < 16; r++) s[r] = sA[r] + sB[r];
        // lane holds k_local = (r&3) + 8*(r>>2) + 4*h (of wave's 32 keys), q = l31

        // ---- softmax over keys (log2 space), in-register ----
        float mp = s[0];
#pragma unroll
        for (int r = 1; r < 16; r++) mp = fmaxf(mp, s[r]);
        mp = fmaxf(mp, __shfl_xor(mp, 32));

        if (__any(mp > m_run + 11.5f)) {   // defer-max (T13): rescale rarely
            const float mn = fmaxf(m_run, mp);
            const float al = exp2f(m_run - mn);
            m_run = mn;
            l_par *= al;
#pragma unroll
            for (int ct = 0; ct < 4; ct++)
#pragma unroll
                for (int r = 0; r < 16; r++) oacc[ct][r] *= al;   // same q/lane: no shuffle
        }

        float pe[16];
        float ps = 0.0f;
#pragma unroll
        for (int r = 0; r < 16; r++) { pe[r] = exp2f(s[r] - m_run); ps += pe[r]; }
        l_par += ps;

        // ---- P -> PV A-frags fully in registers (lane<->lane^32 exchange) ----
        u32 W[4][2], Xs[4][2];
#pragma unroll
        for (int gg = 0; gg < 4; gg++)
#pragma unroll
            for (int j = 0; j < 2; j++) {
                bf16x2 t = {(bf16)pe[4 * gg + 2 * j], (bf16)pe[4 * gg + 2 * j + 1]};
                W[gg][j] = __builtin_bit_cast(unsigned short, t[0]) |
                           ((u32)__builtin_bit_cast(unsigned short, t[1]) << 16);
                Xs[gg][j] = (u32)__shfl_xor((int)W[gg][j], 32);
            }
        u32x4 pw0 = {h ? Xs[1][0] : W[0][0], h ? Xs[1][1] : W[0][1],
                     h ? W[1][0] : Xs[0][0], h ? W[1][1] : Xs[0][1]};
        u32x4 pw1 = {h ? Xs[3][0] : W[2][0], h ? Xs[3][1] : W[2][1],
                     h ? W[3][0] : Xs[2][0], h ? W[3][1] : Xs[2][1]};
        bf16x8 pa0 = __builtin_bit_cast(bf16x8, pw0);
        bf16x8 pa1 = __builtin_bit_cast(bf16x8, pw1);

        // ---- PV: O[q][c] over this wave's 32 keys, 8 MFMA ----
        __builtin_amdgcn_s_setprio(1);
#pragma unroll
        for (int ct = 0; ct < 4; ct++) {
            bf16x8 vf0 = *reinterpret_cast<const bf16x8*>(
                vtb + VT_BY(ct * 32 + l31, wk * 64 + h * 16));
            oacc[ct] = __builtin_amdgcn_mfma_f32_32x32x16_bf16(pa0, vf0, oacc[ct], 0, 0, 0);
            bf16x8 vf1 = *reinterpret_cast<const bf16x8*>(
                vtb + VT_BY(ct * 32 + l31, wk * 64 + 32 + h * 16));
            oacc[ct] = __builtin_amdgcn_mfma_f32_32x32x16_bf16(pa1, vf1, oacc[ct], 0, 0, 0);
        }
        __builtin_amdgcn_s_setprio(0);

        if (it + 1 < NT) stage_write(cur ^ 1);   // vmcnt wait lands here
        __syncthreads();
    }

    // ---- epilogue: merge lane pair, then 2 wk halves; normalize; residual ----
    const float Lp = l_par + __shfl_xor(l_par, 32);   // m_run identical across pair
    if (l < 32) { s_mx[w][l31] = m_run; s_ls[w][l31] = Lp; }
    __syncthreads();

    const float m_o = s_mx[w ^ 2][l31];
    const float L_o = s_ls[w ^ 2][l31];
    const float m_p = fmaxf(m_run, m_o);
    const float eS  = exp2f(m_run - m_p);
    const float eO  = exp2f(m_o - m_p);
    const float fsc = eS / (Lp * eS + L_o * eO);      // per-lane, q-local

    // O accumulate into sm.o[c][q] over 2 wk phases
    if (wk == 0) {
#pragma unroll
        for (int ct = 0; ct < 4; ct++)
#pragma unroll
            for (int r = 0; r < 16; r++) {
                const int c = ct * 32 + (r & 3) + 8 * (r >> 2) + 4 * h;
                sm.o[c][wq * 32 + l31] = oacc[ct][r] * fsc;
            }
    }
    __syncthreads();
    if (wk == 1) {
#pragma unroll
        for (int ct = 0; ct < 4; ct++)
#pragma unroll
            for (int r = 0; r < 16; r++) {
                const int c = ct * 32 + (r & 3) + 8 * (r >> 2) + 4 * h;
                sm.o[c][wq * 32 + l31] += oacc[ct][r] * fsc;
            }
    }
    __syncthreads();

    // fused residual: out[c][q] = x + 0.002*O, f32x4 along q
    // 2048 slots = 128 c x 16 q-quads (QBLK=64).  (r8 bug: k<16 ran c to 255 OOB.)
#pragma unroll
    for (int k = 0; k < 8; k++) {
        const int slot = tid + k * 256;
        const int c  = slot >> 4;                // 0..127
        const int q4 = (slot & 15) * 4;          // 0..60
        f32x4 xv = *reinterpret_cast<const f32x4*>(xb + (size_t)c * NN + q0 + q4);
        f32x4 oo = *reinterpret_cast<const f32x4*>(&sm.o[c][q4]);
        f32x4 ov;
#pragma unroll
        for (int e = 0; e < 4; e++)
            ov[e] = xv[e] + 0.002f * oo[e];
        *reinterpret_cast<f32x4*>(outb + (size_t)c * NN + q0 + q4) = ov;
    }
}

extern "C" void kernel_launch(void* const* d_in, const int* in_sizes, int n_in,
                              void* d_out, int out_size, void* d_ws, size_t ws_size,
                              hipStream_t stream) {
    const float* x = (const float*)d_in[0];
    float* out = (float*)d_out;
    bf16* ft = (bf16*)d_ws;   // 8 MB

    transpose_to_bf16<<<2048, 256, 0, stream>>>(x, ft);
    attn_kernel<<<512, 256, 0, stream>>>(x, ft, out);
}

// Round 10
// 176.104 us; speedup vs baseline: 2.9046x; 1.1124x over previous
//
#include <hip/hip_runtime.h>

// out = x + 0.002 * einsum('bci,bij->bcj', f, softmax_i(einsum('bci,bcj->bij', f, f)))
// x: [8, 128, 64, 64] fp32.  b=8, c=d=128, n=wh=4096.
// Flash attention, Q=K=V=Ft. 32x32x16 MFMA, 32 q-rows/wave, P in registers
// (v_permlane32_swap_b32), XOR-swizzled LDS K/V tiles, XCD = batch.
// r10 = r6 base (best: 133us) + L2-resident staging:
//   vt stages from xh[b][c][n] bf16 (half bytes, no cvt; ft+xh = 2MB/XCD <= 4MB L2)
//   + permlane32_swap P-exchange (replaces shfl+cndmask), 0.002 folded into fsc.
// ws: ft bf16 [b][n][c] 8MB + xh bf16 [b][c][n] 8MB (fallback to f32 path if ws<16MB).

typedef __bf16 bf16;
typedef bf16 bf16x2 __attribute__((ext_vector_type(2)));
typedef bf16 bf16x4 __attribute__((ext_vector_type(4)));
typedef bf16 bf16x8 __attribute__((ext_vector_type(8)));
typedef float f32x4 __attribute__((ext_vector_type(4)));
typedef float f32x16 __attribute__((ext_vector_type(16)));
typedef unsigned int u32;
typedef u32 u32x4 __attribute__((ext_vector_type(4)));

#define BATCH 8
#define CD 128
#define NN 4096
#define QBLK 128
#define KVB 64
#define NT (NN / KVB)
#define LOG2E 1.44269504f

// XOR swizzle (T2): 16-B granule, bijective per row, same map on write & read.
#define KT_BY(row, colb) (((row) << 8) + ((colb) ^ (((row) & 7) << 4)))  // 256 B rows
#define VT_BY(row, colb) (((row) << 7) + ((colb) ^ (((row) & 7) << 4)))  // 128 B rows

// ---------- kernel 1a: ft[b][n][c] = bf16(x[b][c][n]) — LDS-free transpose ----------
__global__ __launch_bounds__(256) void transpose_to_bf16(const float* __restrict__ x,
                                                         bf16* __restrict__ ft) {
    const u32 g  = blockIdx.x * 256 + threadIdx.x;   // 8*4096*16 = 524288 slots
    const u32 b  = g >> 16;
    const u32 r  = g & 65535;
    const u32 n_lo  = r & 15;
    const u32 c8_lo = (r >> 4) & 3;
    const u32 hi    = r >> 6;
    const u32 c8 = (hi & 3) * 4 + c8_lo;             // 0..15
    const u32 n  = (hi >> 2) * 16 + n_lo;            // 0..4095
    const float* xb = x + (size_t)b * CD * NN;
    bf16x8 o;
#pragma unroll
    for (int e = 0; e < 8; e++)
        o[e] = (bf16)xb[(size_t)(c8 * 8 + e) * NN + n];
    *reinterpret_cast<bf16x8*>(ft + ((size_t)b * NN + n) * CD + c8 * 8) = o;
}

// ---------- kernel 1b: xh = bf16(x), same [b][c][n] layout ----------
__global__ __launch_bounds__(256) void to_bf16(const float* __restrict__ x,
                                               bf16* __restrict__ xh) {
    const int i = blockIdx.x * 256 + threadIdx.x;    // 1048576 f32x4 slots
    f32x4 v = reinterpret_cast<const f32x4*>(x)[i];
    bf16x4 o;
#pragma unroll
    for (int e = 0; e < 4; e++) o[e] = (bf16)v[e];
    reinterpret_cast<bf16x4*>(xh)[i] = o;
}

// ---------- kernel 2: flash attention + fused residual ----------
// 256 blocks (XCD=batch, 32 q-tiles of 128), 512 threads = 8 waves (4wq x 2wk).
// Wave: 32 q-rows x 32 keys per iter, 16 MFMA (32x32x16), KV tile 64, dbuf LDS.
template <bool XH>
__global__ __launch_bounds__(512, 2) void attn_kernel(const float* __restrict__ x,
                                                      const bf16* __restrict__ ft,
                                                      const bf16* __restrict__ xh,
                                                      float* __restrict__ out) {
    const int tid = threadIdx.x;
    const int w   = tid >> 6;
    const int wq  = w & 3;      // q-group: 32 rows
    const int wk  = w >> 2;     // key-half: 32 keys
    const int l   = tid & 63;
    const int l31 = l & 31;
    const int h   = l >> 5;

    const int batch = blockIdx.x & 7;            // round-robin dispatch -> XCD = batch
    const int q0    = (blockIdx.x >> 3) * QBLK;

    const bf16*  ftb  = ft  + (size_t)batch * NN * CD;
    const bf16*  xhb  = XH ? xh + (size_t)batch * CD * NN : nullptr;
    const float* xb   = x   + (size_t)batch * CD * NN;
    float*       outb = out + (size_t)batch * CD * NN;

    __shared__ union {
        struct {
            bf16 kt[2][KVB * 128];   // [key][c] swizzled, 16 KB/buf
            bf16 vt[2][CD * KVB];    // [c][key] swizzled, 16 KB/buf
        } s;
        float o[CD][132];            // epilogue O merge [c][q]
    } sm;
    __shared__ float s_mx[8][32], s_ls[8][32];

    // Q frags (B-operand): q = q0+wq*32+l31, c = kst*16 + h*8 + e; folded log2e
    bf16x8 qf[8];
    {
        const bf16* qp = ftb + (size_t)(q0 + wq * 32 + l31) * CD + h * 8;
#pragma unroll
        for (int kst = 0; kst < 8; kst++) {
            bf16x8 t = *reinterpret_cast<const bf16x8*>(qp + kst * 16);
#pragma unroll
            for (int e = 0; e < 8; e++) qf[kst][e] = (bf16)((float)t[e] * LOG2E);
        }
    }

    // ---- staging: kt from ft (bf16 copy); vt from xh (bf16 copy) or x (f32+cvt) ----
    bf16x8 kreg[2];
    bf16x8 vregh[2];
    f32x4  vregf[4];
    auto stage_load = [&](int i0) {
#pragma unroll
        for (int j = 0; j < 2; j++) {                 // kt: 64 rows x 256B
            const int slot = tid + j * 512;
            kreg[j] = *reinterpret_cast<const bf16x8*>(
                ftb + (size_t)(i0 + (slot >> 4)) * CD + (slot & 15) * 8);
        }
        if constexpr (XH) {
#pragma unroll
            for (int j = 0; j < 2; j++) {             // vt: 128 c-rows x 64 keys (bf16)
                const int slot = tid + j * 512;       // 1024 slots of 16B
                vregh[j] = *reinterpret_cast<const bf16x8*>(
                    xhb + (size_t)(slot >> 3) * NN + i0 + (slot & 7) * 8);
            }
        } else {
#pragma unroll
            for (int j = 0; j < 4; j++) {             // vt: 128 c-rows x 64 keys (f32)
                const int slot = tid + j * 512;
                vregf[j] = *reinterpret_cast<const f32x4*>(
                    xb + (size_t)(slot >> 4) * NN + i0 + (slot & 15) * 4);
            }
        }
    };
    auto stage_write = [&](int buf) {
        char* ktb = (char*)sm.s.kt[buf];
        char* vtb = (char*)sm.s.vt[buf];
#pragma unroll
        for (int j = 0; j < 2; j++) {
            const int slot = tid + j * 512;
            *reinterpret_cast<bf16x8*>(ktb + KT_BY(slot >> 4, (slot & 15) * 16)) = kreg[j];
        }
        if constexpr (XH) {
#pragma unroll
            for (int j = 0; j < 2; j++) {
                const int slot = tid + j * 512;
                *reinterpret_cast<bf16x8*>(vtb + VT_BY(slot >> 3, (slot & 7) * 16)) = vregh[j];
            }
        } else {
#pragma unroll
            for (int j = 0; j < 4; j++) {
                const int slot = tid + j * 512;
                bf16x4 t;
#pragma unroll
                for (int e = 0; e < 4; e++) t[e] = (bf16)vregf[j][e];
                *reinterpret_cast<bf16x4*>(vtb + VT_BY(slot >> 4, (slot & 15) * 8)) = t;
            }
        }
    };

    f32x16 oacc[4];
#pragma unroll
    for (int ct = 0; ct < 4; ct++)
#pragma unroll
        for (int r = 0; r < 16; r++) oacc[ct][r] = 0.0f;
    float m_run = -1e30f;   // running max (log2 units) for q = l31
    float l_par = 0.0f;     // per-lane partial denominator (16-key share)

    stage_load(0);
    stage_write(0);
    __syncthreads();

    for (int it = 0; it < NT; ++it) {
        const int cur = it & 1;
        if (it + 1 < NT) stage_load((it + 1) * KVB);   // in flight under compute (T14)

        const char* ktb = (const char*)sm.s.kt[cur];
        const char* vtb = (const char*)sm.s.vt[cur];

        // ---- QK^T: S'[key=wk*32+rowmap][q=l31], 8 MFMA, 2 acc chains ----
        f32x16 sA, sB;
#pragma unroll
        for (int r = 0; r < 16; r++) { sA[r] = 0.0f; sB[r] = 0.0f; }
        __builtin_amdgcn_s_setprio(1);
#pragma unroll
        for (int kst = 0; kst < 8; kst += 2) {
            bf16x8 kf0 = *reinterpret_cast<const bf16x8*>(
                ktb + KT_BY(wk * 32 + l31, kst * 32 + h * 16));
            bf16x8 kf1 = *reinterpret_cast<const bf16x8*>(
                ktb + KT_BY(wk * 32 + l31, (kst + 1) * 32 + h * 16));
            sA = __builtin_amdgcn_mfma_f32_32x32x16_bf16(kf0, qf[kst], sA, 0, 0, 0);
            sB = __builtin_amdgcn_mfma_f32_32x32x16_bf16(kf1, qf[kst + 1], sB, 0, 0, 0);
        }
        __builtin_amdgcn_s_setprio(0);
        float s[16];
#pragma unroll
        for (int r = 0; r < 16; r++) s[r] = sA[r] + sB[r];
        // lane holds k_local = (r&3) + 8*(r>>2) + 4*h (of wave's 32 keys), q = l31

        // ---- softmax over keys (log2 space), in-register ----
        float mp = s[0];
#pragma unroll
        for (int r = 1; r < 16; r++) mp = fmaxf(mp, s[r]);
        mp = fmaxf(mp, __shfl_xor(mp, 32));

        if (__any(mp > m_run + 11.5f)) {   // defer-max (T13): rescale rarely
            const float mn = fmaxf(m_run, mp);
            const float al = exp2f(m_run - mn);
            m_run = mn;
            l_par *= al;
#pragma unroll
            for (int ct = 0; ct < 4; ct++)
#pragma unroll
                for (int r = 0; r < 16; r++) oacc[ct][r] *= al;   // same q/lane: no shuffle
        }

        float pe[16];
        float ps = 0.0f;
#pragma unroll
        for (int r = 0; r < 16; r++) { pe[r] = exp2f(s[r] - m_run); ps += pe[r]; }
        l_par += ps;

        // ---- P -> PV A-frags in registers via v_permlane32_swap_b32 (T12) ----
        // W[g][j] packs k = 8g + 4h + {2j, 2j+1}. After swap(W[a],W[b]):
        //   W[a] = {A.lo, B.lo}, W[b] = {A.hi, B.hi}  == the exchange QK^T A-frags need.
        u32 W[4][2];
#pragma unroll
        for (int gg = 0; gg < 4; gg++)
#pragma unroll
            for (int j = 0; j < 2; j++) {
                bf16x2 t = {(bf16)pe[4 * gg + 2 * j], (bf16)pe[4 * gg + 2 * j + 1]};
                W[gg][j] = __builtin_bit_cast(unsigned short, t[0]) |
                           ((u32)__builtin_bit_cast(unsigned short, t[1]) << 16);
            }
        asm volatile("v_permlane32_swap_b32 %0, %1" : "+v"(W[0][0]), "+v"(W[1][0]));
        asm volatile("v_permlane32_swap_b32 %0, %1" : "+v"(W[0][1]), "+v"(W[1][1]));
        asm volatile("v_permlane32_swap_b32 %0, %1" : "+v"(W[2][0]), "+v"(W[3][0]));
        asm volatile("v_permlane32_swap_b32 %0, %1" : "+v"(W[2][1]), "+v"(W[3][1]));
        u32x4 pw0 = {W[0][0], W[0][1], W[1][0], W[1][1]};
        u32x4 pw1 = {W[2][0], W[2][1], W[3][0], W[3][1]};
        bf16x8 pa0 = __builtin_bit_cast(bf16x8, pw0);
        bf16x8 pa1 = __builtin_bit_cast(bf16x8, pw1);

        // ---- PV: O[q][c] over this wave's 32 keys, 8 MFMA ----
        __builtin_amdgcn_s_setprio(1);
#pragma unroll
        for (int ct = 0; ct < 4; ct++) {
            bf16x8 vf0 = *reinterpret_cast<const bf16x8*>(
                vtb + VT_BY(ct * 32 + l31, wk * 64 + h * 16));
            oacc[ct] = __builtin_amdgcn_mfma_f32_32x32x16_bf16(pa0, vf0, oacc[ct], 0, 0, 0);
            bf16x8 vf1 = *reinterpret_cast<const bf16x8*>(
                vtb + VT_BY(ct * 32 + l31, wk * 64 + 32 + h * 16));
            oacc[ct] = __builtin_amdgcn_mfma_f32_32x32x16_bf16(pa1, vf1, oacc[ct], 0, 0, 0);
        }
        __builtin_amdgcn_s_setprio(0);

        if (it + 1 < NT) stage_write(cur ^ 1);   // vmcnt wait lands here
        __syncthreads();
    }

    // ---- epilogue: merge lane pair, then 2 wk halves; normalize; residual ----
    const float Lp = l_par + __shfl_xor(l_par, 32);   // m_run identical across pair
    if (l < 32) { s_mx[w][l31] = m_run; s_ls[w][l31] = Lp; }
    __syncthreads();

    const float m_o = s_mx[w ^ 4][l31];
    const float L_o = s_ls[w ^ 4][l31];
    const float m_p = fmaxf(m_run, m_o);
    const float eS  = exp2f(m_run - m_p);
    const float eO  = exp2f(m_o - m_p);
    const float fsc = 0.002f * eS / (Lp * eS + L_o * eO);   // 0.002 folded in

    // O accumulate into sm.o[c][q] over 2 wk phases
    if (wk == 0) {
#pragma unroll
        for (int ct = 0; ct < 4; ct++)
#pragma unroll
            for (int r = 0; r < 16; r++) {
                const int c = ct * 32 + (r & 3) + 8 * (r >> 2) + 4 * h;
                sm.o[c][wq * 32 + l31] = oacc[ct][r] * fsc;
            }
    }
    __syncthreads();
    if (wk == 1) {
#pragma unroll
        for (int ct = 0; ct < 4; ct++)
#pragma unroll
            for (int r = 0; r < 16; r++) {
                const int c = ct * 32 + (r & 3) + 8 * (r >> 2) + 4 * h;
                sm.o[c][wq * 32 + l31] += oacc[ct][r] * fsc;
            }
    }
    __syncthreads();

    // fused residual: out[c][q] = x + O, f32x4 along q (4096 slots)
#pragma unroll
    for (int k = 0; k < 8; k++) {
        const int slot = tid + k * 512;
        const int c  = slot >> 5;                // 0..127
        const int q4 = (slot & 31) * 4;          // 0..124
        f32x4 xv = *reinterpret_cast<const f32x4*>(xb + (size_t)c * NN + q0 + q4);
        f32x4 oo = *reinterpret_cast<const f32x4*>(&sm.o[c][q4]);
        f32x4 ov;
#pragma unroll
        for (int e = 0; e < 4; e++)
            ov[e] = xv[e] + oo[e];
        *reinterpret_cast<f32x4*>(outb + (size_t)c * NN + q0 + q4) = ov;
    }
}

extern "C" void kernel_launch(void* const* d_in, const int* in_sizes, int n_in,
                              void* d_out, int out_size, void* d_ws, size_t ws_size,
                              hipStream_t stream) {
    const float* x = (const float*)d_in[0];
    float* out = (float*)d_out;
    bf16* ft = (bf16*)d_ws;                               // 8 MB
    bf16* xh = ft + (size_t)BATCH * NN * CD;              // +8 MB

    const bool use_xh = ws_size >= ((size_t)32u << 20) ? true
                       : ws_size >= ((size_t)16u << 20);  // need 16 MB for ft+xh

    transpose_to_bf16<<<2048, 256, 0, stream>>>(x, ft);
    if (use_xh) {
        to_bf16<<<4096, 256, 0, stream>>>(x, xh);
        attn_kernel<true><<<256, 512, 0, stream>>>(x, ft, xh, out);
    } else {
        attn_kernel<false><<<256, 512, 0, stream>>>(x, ft, nullptr, out);
    }
}